// Round 9
// baseline (7882.863 us; speedup 1.0000x reference)
//
#include <hip/hip_runtime.h>

typedef unsigned short u16;
typedef __attribute__((ext_vector_type(4))) float f32x4;
typedef __attribute__((ext_vector_type(8))) short bf16x8;
typedef __attribute__((ext_vector_type(8))) unsigned short u16x8;
typedef __attribute__((ext_vector_type(4))) unsigned short u16x4;

__device__ __forceinline__ u16 f2bf(float f) {
  union { float f; unsigned u; } v; v.f = f;
  unsigned r = v.u + 0x7FFFu + ((v.u >> 16) & 1u);
  return (u16)(r >> 16);
}
__device__ __forceinline__ float bf2f(u16 h) {
  union { unsigned u; float f; } v; v.u = ((unsigned)h) << 16; return v.f;
}

__device__ __forceinline__ void gload_lds16(const void* g, void* l) {
  __builtin_amdgcn_global_load_lds((const __attribute__((address_space(1))) void*)g,
                                   (__attribute__((address_space(3))) void*)l, 16, 0, 0);
}

// ---------------- prep kernels ----------------

__global__ void k_zero(u16x8* __restrict__ p, int n8) {
  int i = blockIdx.x * blockDim.x + threadIdx.x;
  int stride = gridDim.x * blockDim.x;
  u16x8 z = (u16x8)0;
  for (; i < n8; i += stride) p[i] = z;
}

__global__ void k_cvt_x(const float* __restrict__ in, u16* __restrict__ out, int n4) {
  int i = blockIdx.x * blockDim.x + threadIdx.x;
  int stride = gridDim.x * blockDim.x;
  const f32x4* in4 = (const f32x4*)in;
  u16x4* out4 = (u16x4*)out;
  for (; i < n4; i += stride) {
    f32x4 v = in4[i];
    u16x4 o;
    o[0] = f2bf(v[0]); o[1] = f2bf(v[1]); o[2] = f2bf(v[2]); o[3] = f2bf(v[3]);
    out4[i] = o;
  }
}

// LDS-tiled transpose: w [K][1024] f32 -> outT [1024][K] bf16, 64x64 tiles.
// Coalesced reads (f32x4) AND coalesced writes (u16x8) -- the old per-column
// writer had ~32x write amplification (2B scattered at 2KB stride).
__global__ void k_prep_wt(const float* __restrict__ wq, const float* __restrict__ wo,
                          const float* __restrict__ wk, const float* __restrict__ wv,
                          u16* __restrict__ WQ1T, u16* __restrict__ WO1T,
                          u16* __restrict__ WK1T, u16* __restrict__ WV1T) {
  __shared__ u16 tile[64][72];
  int bid = blockIdx.x;
  const float* w; u16* o; int K;
  if (bid < 256)      { w = wq; o = WQ1T; K = 1024; }
  else if (bid < 512) { w = wo; o = WO1T; K = 1024; bid -= 256; }
  else if (bid < 704) { w = wk; o = WK1T; K = 768;  bid -= 512; }
  else                { w = wv; o = WV1T; K = 768;  bid -= 704; }
  const int ti = bid >> 4, tj = bid & 15;     // ti: K/64 tiles, tj: 16 n-tiles
  const int t = threadIdx.x;
  const int r = t >> 2, cq = (t & 3) * 16;

  const float* src = w + (size_t)(ti * 64 + r) * 1024 + tj * 64 + cq;
#pragma unroll
  for (int j4 = 0; j4 < 4; ++j4) {
    f32x4 v = *(const f32x4*)(src + j4 * 4);
#pragma unroll
    for (int e = 0; e < 4; ++e) tile[r][cq + j4 * 4 + e] = f2bf(v[e]);
  }
  __syncthreads();

  u16 vals[16];
#pragma unroll
  for (int j = 0; j < 16; ++j) vals[j] = tile[cq + j][r];
  u16* dst = o + (size_t)(tj * 64 + r) * K + ti * 64 + cq;
  *(u16x8*)dst = *(u16x8*)&vals[0];
  *(u16x8*)(dst + 8) = *(u16x8*)&vals[8];
}

// y [1232][768] f32 -> yb bf16 (straight cvt)
__global__ void k_prep_y(const float* __restrict__ y, u16* __restrict__ yb, int n4) {
  int i = blockIdx.x * blockDim.x + threadIdx.x;
  int stride = gridDim.x * blockDim.x;
  const f32x4* in4 = (const f32x4*)y;
  u16x4* out4 = (u16x4*)yb;
  for (; i < n4; i += stride) {
    f32x4 v = in4[i];
    u16x4 o;
    o[0] = f2bf(v[0]); o[1] = f2bf(v[1]); o[2] = f2bf(v[2]); o[3] = f2bf(v[3]);
    out4[i] = o;
  }
}

// ---------------- K+V projections, merged, m97-style 128^2 ----------------
__global__ __launch_bounds__(256, 2) void k_gemm_kv(
    const u16* __restrict__ A,
    const u16* __restrict__ BK1, const float* __restrict__ bkb, u16* __restrict__ KTo,
    const u16* __restrict__ BV1, const float* __restrict__ bvb, u16* __restrict__ VTo)
{
  const int M = 1232, Kdim = 768;
  __shared__ u16 sA[128 * 32];
  __shared__ u16 sB[128 * 32];
  const int t = threadIdx.x;
  const int half = blockIdx.x >= 80;
  const int bb = blockIdx.x - half * 80;
  const u16* B = half ? BV1 : BK1;
  const float* bias = half ? bvb : bkb;
  u16* outp = half ? VTo : KTo;
  const int bm = bb / 8, bn = bb % 8;
  const int m0 = bm * 128, n0 = bn * 128;
  const int l = t & 63, wv_ = t >> 6;
  const int lr = l & 15, lg = l >> 4;
  const int wm = (wv_ >> 1) * 64, wn = (wv_ & 1) * 64;

  const int srow = t >> 2;
  const int ssw = ((t >> 2) & 3) ^ ((t >> 4) & 3);
  const int scol = ((t & 3) ^ ssw) * 8;
  char* ldsA = (char*)sA;
  char* ldsB = (char*)sB;
  const int ldsoff = wv_ * 1024;

  const int swl = (lr & 3) ^ ((lr >> 2) & 3);
  const int rds = (lg ^ swl) * 8;

  f32x4 acc[4][4] = {};

  for (int kt = 0; kt < Kdim / 32; ++kt) {
    const int k0 = kt * 32;
    __syncthreads();
    {
      int r1 = m0 + srow;       if (r1 > M - 1) r1 = M - 1;
      int r2 = m0 + 64 + srow;  if (r2 > M - 1) r2 = M - 1;
      gload_lds16(A + (size_t)r1 * Kdim + k0 + scol, ldsA + 0    + ldsoff);
      gload_lds16(A + (size_t)r2 * Kdim + k0 + scol, ldsA + 4096 + ldsoff);
      gload_lds16(B + (size_t)(n0 + srow) * Kdim + k0 + scol,      ldsB + 0    + ldsoff);
      gload_lds16(B + (size_t)(n0 + 64 + srow) * Kdim + k0 + scol, ldsB + 4096 + ldsoff);
    }
    __syncthreads();
    bf16x8 af[4], bfr[4];
#pragma unroll
    for (int mt = 0; mt < 4; ++mt)
      af[mt] = *(const bf16x8*)&sA[(wm + mt * 16 + lr) * 32 + rds];
#pragma unroll
    for (int nt = 0; nt < 4; ++nt)
      bfr[nt] = *(const bf16x8*)&sB[(wn + nt * 16 + lr) * 32 + rds];
#pragma unroll
    for (int mt = 0; mt < 4; ++mt)
#pragma unroll
      for (int nt = 0; nt < 4; ++nt)
        acc[mt][nt] = __builtin_amdgcn_mfma_f32_16x16x32_bf16(af[mt], bfr[nt], acc[mt][nt], 0, 0, 0);
  }

#pragma unroll
  for (int mt = 0; mt < 4; ++mt) {
#pragma unroll
    for (int nt = 0; nt < 4; ++nt) {
      const int gc = n0 + wn + nt * 16 + lr;
      const float bb2 = bias[gc];
#pragma unroll
      for (int r = 0; r < 4; ++r) {
        const int gr = m0 + wm + mt * 16 + lg * 4 + r;
        const float v = acc[mt][nt][r] + bb2;
        if (gr < M) {
          int bI = gr / 77, s = gr - bI * 77;
          int hh = gc >> 6, d = gc & 63;
          if (!half)
            outp[(((size_t)bI * 16 + hh) * 96 + s) * 64 + d] = f2bf(v);
          else
            outp[(((size_t)bI * 16 + hh) * 64 + d) * 96 + s] = f2bf(v);
        }
      }
    }
  }
}

// ---------------- big GEMM: 256x256, BK=32, A-only LDS (3 bufs), B via registers ----------------
// M=65536, N=1024, K=1024. A [M][1024] bf16, B^T [1024][1024] bf16 (2MB, L2-resident).
// 512 thr = 8 waves (2M x 4N), wave tile 128x64.
// B: global->register fragments, 1 K-tile ahead, reg-double-buffered. The compiler
// tracks these loads and emits its own counted vmcnt before first MFMA use.
// A: LDS triple buffer 3x16KB = 48KB -> 3 blocks/CU (24 waves) for TLP de-phasing.
// LDS pipe now carries only A (8 reads + 2 stage-writes per wave per K-tile ~ 320 cyc/CU
// vs MFMA 621 cyc/CU) -> MFMA is the only saturated pipe.
// Ledger: iter c issues [LD_B(c+1):4, STAGE_A(c+2):2]. Queue at wait (old->new):
// [B(c):4, A(c+1):2, B(c+1):4, A(c+2):2] -> vmcnt(6) retires B(c)+A(c+1) exactly.
// Order per iter (r7 lesson): reads; issues; vmcnt(6); sched_barrier; s_barrier; MFMA; s_barrier.
template <int EPI>
__global__ __launch_bounds__(512, 6) void gemm256(
    const u16* __restrict__ A, const u16* __restrict__ Bp,
    const float* __restrict__ bias, void* __restrict__ outp)
{
  __shared__ char lds[49152];
  const int t = threadIdx.x;
  const int cpx = (int)gridDim.x >> 3;
  const int swz = ((int)blockIdx.x & 7) * cpx + ((int)blockIdx.x >> 3);
  const int bm = swz >> 2, bn = swz & 3;
  const int m0 = bm * 256, n0 = bn * 256;
  const int w = t >> 6, l = t & 63, lr = l & 15, lg = l >> 4;
  const int wm = w >> 2, wn = w & 3;   // 2 M-waves x 4 N-waves, wave tile 128x64

  // A staging: thread t -> LDS byte t*16 (row t>>2 per 128-row issue, slot t&3);
  // global k-slot pre-swizzled: LDS[row][s] holds global slot s ^ (r&3) ^ ((r>>2)&3)
  const int srow = t >> 2;
  const int scol = ((t & 3) ^ ((t >> 2) & 3) ^ ((t >> 4) & 3)) * 8;  // elems
  const int rsw = (lg ^ (lr & 3) ^ ((lr >> 2) & 3)) << 4;            // read swizzle, bytes
  const int arow = wm * 128 + lr;

  // B per-lane base: col = n0 + wn*64 + nt*16 + lr, k = kt*32 + lg*8
  const u16* bptr = Bp + (size_t)(n0 + wn * 64 + lr) * 1024 + lg * 8;

  f32x4 acc[8][4] = {};

#define RD_A(dst, rbb) { _Pragma("unroll") for (int q = 0; q < 8; ++q) \
    dst[q] = *(const bf16x8*)(lds + (rbb) + ((arow + q * 16) << 6) + rsw); }
#define LD_B(dst, kt) { _Pragma("unroll") for (int nt = 0; nt < 4; ++nt) \
    dst[nt] = *(const bf16x8*)(bptr + (size_t)nt * 16384 + (kt) * 32); }
#define STAGE_A(kt, sbb) { \
    gload_lds16(A + (size_t)(m0 + srow) * 1024 + (kt) * 32 + scol,       lds + (sbb) + t * 16); \
    gload_lds16(A + (size_t)(m0 + 128 + srow) * 1024 + (kt) * 32 + scol, lds + (sbb) + 8192 + t * 16); }
#define MM(a_, b_) { __builtin_amdgcn_s_setprio(1); \
  _Pragma("unroll") for (int q = 0; q < 8; ++q) \
    _Pragma("unroll") for (int nt = 0; nt < 4; ++nt) \
      acc[q][nt] = __builtin_amdgcn_mfma_f32_16x16x32_bf16(a_[q], b_[nt], acc[q][nt], 0, 0, 0); \
  __builtin_amdgcn_s_setprio(0); }
#define BAR __builtin_amdgcn_s_barrier()
#define SB0 __builtin_amdgcn_sched_barrier(0)
#define VM6 asm volatile("s_waitcnt vmcnt(6)" ::: "memory")

  bf16x8 bA[4], bB[4];

  // prologue: stage A tiles 0,1; load B(0). Queue [A0:2, A1:2, B0:4] -> vmcnt(6)
  // retires A0; B0 readiness enforced by compiler before first MFMA use.
  STAGE_A(0, 0);
  STAGE_A(1, 16384);
  LD_B(bA, 0);
  VM6; SB0; BAR;

  int rb = 0, sb = 32768;
#pragma unroll 1
  for (int c = 0; c < 32; c += 2) {
    {
      bf16x8 a_[8];
      RD_A(a_, rb);
      LD_B(bB, c + 1);                       // c+1 <= 31 always here
      int k2 = c + 2; if (k2 > 31) k2 = 31;  // tail: dummy re-stage into retired buf
      STAGE_A(k2, sb);
      VM6; SB0; BAR;
      MM(a_, bA);
      BAR;
      rb += 16384; if (rb == 49152) rb = 0;
      sb += 16384; if (sb == 49152) sb = 0;
    }
    {
      bf16x8 a_[8];
      RD_A(a_, rb);
      int k1 = c + 2; if (k1 > 31) k1 = 31;
      LD_B(bA, k1);
      int k2 = c + 3; if (k2 > 31) k2 = 31;
      STAGE_A(k2, sb);
      VM6; SB0; BAR;
      MM(a_, bB);
      BAR;
      rb += 16384; if (rb == 49152) rb = 0;
      sb += 16384; if (sb == 49152) sb = 0;
    }
  }
  asm volatile("s_waitcnt vmcnt(0)" ::: "memory");  // drain dummy stages before endpgm
  SB0;

#undef RD_A
#undef LD_B
#undef STAGE_A
#undef MM
#undef BAR
#undef SB0
#undef VM6

  // epilogue: C row = m0 + wm*128 + q*16 + lg*4 + r ; col = n0 + wn*64 + nt*16 + lr
#pragma unroll
  for (int q = 0; q < 8; ++q) {
#pragma unroll
    for (int nt = 0; nt < 4; ++nt) {
      const int gc = n0 + wn * 64 + nt * 16 + lr;
      const float bb = bias[gc];
#pragma unroll
      for (int r = 0; r < 4; ++r) {
        const int gr = m0 + wm * 128 + q * 16 + lg * 4 + r;
        const float v = acc[q][nt][r] + bb;
        if constexpr (EPI == 0) {
          ((u16*)outp)[(size_t)gr * 1024 + gc] = f2bf(v);
        } else {
          ((float*)outp)[(size_t)gr * 1024 + gc] = v;
        }
      }
    }
  }
}

// ---------------- fused attention ----------------
__global__ __launch_bounds__(256) void k_attn(const u16* __restrict__ KT,
                                              const u16* __restrict__ VT,
                                              u16* __restrict__ QB)
{
  __shared__ u16 sK[96 * 72];
  __shared__ u16 sV[64 * 104];
  __shared__ u16 sP[4][32 * 104];

  const int bid = blockIdx.x;
  const int h = bid & 15, b = (bid >> 4) & 15, blk = bid >> 8;
  const int t = threadIdx.x;

  const u16* gK = KT + (size_t)(b * 16 + h) * (96 * 64);
  const u16* gV = VT + (size_t)(b * 16 + h) * (64 * 96);
#pragma unroll
  for (int c = 0; c < 3; ++c) {
    int e = t * 8 + c * 2048;
    { int row = e >> 6, col = e & 63;
      *(u16x8*)&sK[row * 72 + col] = *(const u16x8*)&gK[e]; }
    { int row = e / 96, col = e - (e / 96) * 96;
      *(u16x8*)&sV[row * 104 + col] = *(const u16x8*)&gV[e]; }
  }
  __syncthreads();

  const int l = t & 63, w = t >> 6, lr = l & 15, lg = l >> 4;
  const size_t rowbase = (size_t)b * 4096 + blk * 128 + w * 32;

  bf16x8 aq[2][2];
#pragma unroll
  for (int mt = 0; mt < 2; ++mt)
#pragma unroll
    for (int ks = 0; ks < 2; ++ks)
      aq[mt][ks] = *(const bf16x8*)&QB[(rowbase + mt * 16 + lr) * 1024 + h * 64 + ks * 32 + lg * 8];

  f32x4 s_[2][5] = {};
#pragma unroll
  for (int nt = 0; nt < 5; ++nt) {
#pragma unroll
    for (int ks = 0; ks < 2; ++ks) {
      bf16x8 bk = *(const bf16x8*)&sK[(nt * 16 + lr) * 72 + ks * 32 + lg * 8];
#pragma unroll
      for (int mt = 0; mt < 2; ++mt)
        s_[mt][nt] = __builtin_amdgcn_mfma_f32_16x16x32_bf16(aq[mt][ks], bk, s_[mt][nt], 0, 0, 0);
    }
  }
#pragma unroll
  for (int mt = 0; mt < 2; ++mt)
#pragma unroll
    for (int nt = 0; nt < 5; ++nt)
#pragma unroll
      for (int r = 0; r < 4; ++r)
        s_[mt][nt][r] *= 0.125f;
  if (lr >= 13) {
#pragma unroll
    for (int mt = 0; mt < 2; ++mt)
#pragma unroll
      for (int r = 0; r < 4; ++r)
        s_[mt][4][r] = -1e30f;
  }

  float ri[2][4];
#pragma unroll
  for (int mt = 0; mt < 2; ++mt) {
#pragma unroll
    for (int r = 0; r < 4; ++r) {
      float m1 = s_[mt][0][r];
#pragma unroll
      for (int nt = 1; nt < 5; ++nt) m1 = fmaxf(m1, s_[mt][nt][r]);
      m1 = fmaxf(m1, __shfl_xor(m1, 1, 64));
      m1 = fmaxf(m1, __shfl_xor(m1, 2, 64));
      m1 = fmaxf(m1, __shfl_xor(m1, 4, 64));
      m1 = fmaxf(m1, __shfl_xor(m1, 8, 64));
      float s1 = 0.f;
#pragma unroll
      for (int nt = 0; nt < 5; ++nt) {
        float e = __expf(s_[mt][nt][r] - m1);
        s_[mt][nt][r] = e;
        s1 += e;
      }
      s1 += __shfl_xor(s1, 1, 64);
      s1 += __shfl_xor(s1, 2, 64);
      s1 += __shfl_xor(s1, 4, 64);
      s1 += __shfl_xor(s1, 8, 64);
      ri[mt][r] = 1.0f / s1;
    }
  }

#pragma unroll
  for (int mt = 0; mt < 2; ++mt)
#pragma unroll
    for (int nt = 0; nt < 5; ++nt)
#pragma unroll
      for (int r = 0; r < 4; ++r)
        sP[w][(mt * 16 + lg * 4 + r) * 104 + nt * 16 + lr] = f2bf(s_[mt][nt][r] * ri[mt][r]);
#pragma unroll
  for (int mt = 0; mt < 2; ++mt)
#pragma unroll
    for (int r = 0; r < 4; ++r)
      sP[w][(mt * 16 + lg * 4 + r) * 104 + 80 + lr] = 0;

  f32x4 o_[2][4] = {};
#pragma unroll
  for (int ks = 0; ks < 3; ++ks) {
    bf16x8 ap[2];
#pragma unroll
    for (int mt = 0; mt < 2; ++mt)
      ap[mt] = *(const bf16x8*)&sP[w][(mt * 16 + lr) * 104 + ks * 32 + lg * 8];
#pragma unroll
    for (int nt = 0; nt < 4; ++nt) {
      bf16x8 bv = *(const bf16x8*)&sV[(nt * 16 + lr) * 104 + ks * 32 + lg * 8];
#pragma unroll
      for (int mt = 0; mt < 2; ++mt)
        o_[mt][nt] = __builtin_amdgcn_mfma_f32_16x16x32_bf16(ap[mt], bv, o_[mt][nt], 0, 0, 0);
    }
  }

#pragma unroll
  for (int mt = 0; mt < 2; ++mt)
#pragma unroll
    for (int nt = 0; nt < 4; ++nt)
#pragma unroll
      for (int r = 0; r < 4; ++r)
        QB[(rowbase + mt * 16 + lg * 4 + r) * 1024 + h * 64 + nt * 16 + lr] = f2bf(o_[mt][nt][r]);
}

// ---------------- launch ----------------

extern "C" void kernel_launch(void* const* d_in, const int* in_sizes, int n_in,
                              void* d_out, int out_size, void* d_ws, size_t ws_size,
                              hipStream_t stream) {
  const float* x  = (const float*)d_in[0];
  const float* y  = (const float*)d_in[1];
  const float* wq = (const float*)d_in[2];
  const float* bq = (const float*)d_in[3];
  const float* wk = (const float*)d_in[4];
  const float* bk = (const float*)d_in[5];
  const float* wv = (const float*)d_in[6];
  const float* bv = (const float*)d_in[7];
  const float* wo = (const float*)d_in[8];
  const float* bo = (const float*)d_in[9];

  char* ws = (char*)d_ws;
  u16* QB   = (u16*)(ws + 0);            // 65536x1024 bf16 = 128 MB (Q, then attn out in-place)
  u16* WQ1T = (u16*)(ws + 134217728);    // [1024][1024] bf16, 2 MB
  u16* WO1T = (u16*)(ws + 136314880);    // 2 MB
  u16* WK1T = (u16*)(ws + 138412032);    // [1024][768] bf16, 1.5 MB
  u16* WV1T = (u16*)(ws + 139984896);    // 1.5 MB
  u16* YB   = (u16*)(ws + 141557760);    // [1232][768] bf16, 1.85 MB
  u16* KT   = (u16*)(ws + 143654912);    // [16][16][96][64] bf16, 3 MB
  u16* VT   = (u16*)(ws + 146800640);    // [16][16][64][96] bf16, 3 MB

  u16*   XB  = (u16*)d_out;   // x as bf16, first 128 MB of d_out (consumed before final write)
  float* OUT = (float*)d_out;

  // prep
  k_zero<<<768, 256, 0, stream>>>((u16x8*)KT, 393216);          // zero KT+VT (adjacent, 6 MB)
  k_cvt_x<<<4096, 256, 0, stream>>>(x, XB, 16777216);
  k_prep_wt<<<896, 256, 0, stream>>>(wq, wo, wk, wv, WQ1T, WO1T, WK1T, WV1T);
  k_prep_y<<<924, 256, 0, stream>>>(y, YB, 236544);

  // K+V projections (one launch): M=1232, K=768
  k_gemm_kv<<<160, 256, 0, stream>>>(YB, WK1T, bk, KT, WV1T, bv, VT);

  // Q projection: 256x256 BK=32, A-LDS triple buffer + B-in-regs, grid 256 bm x 4 bn
  gemm256<0><<<1024, 512, 0, stream>>>(XB, WQ1T, bq, QB);

  // fused attention, in-place QB -> attn_out
  k_attn<<<8192, 256, 0, stream>>>(KT, VT, QB);

  // output projection -> f32 d_out
  gemm256<1><<<1024, 512, 0, stream>>>(QB, WO1T, bo, OUT);
}

// Round 10
// 666.904 us; speedup vs baseline: 11.8201x; 11.8201x over previous
//
#include <hip/hip_runtime.h>

typedef unsigned short u16;
typedef __attribute__((ext_vector_type(4))) float f32x4;
typedef __attribute__((ext_vector_type(8))) short bf16x8;
typedef __attribute__((ext_vector_type(8))) unsigned short u16x8;
typedef __attribute__((ext_vector_type(4))) unsigned short u16x4;

__device__ __forceinline__ u16 f2bf(float f) {
  union { float f; unsigned u; } v; v.f = f;
  unsigned r = v.u + 0x7FFFu + ((v.u >> 16) & 1u);
  return (u16)(r >> 16);
}
__device__ __forceinline__ float bf2f(u16 h) {
  union { unsigned u; float f; } v; v.u = ((unsigned)h) << 16; return v.f;
}

__device__ __forceinline__ void gload_lds16(const void* g, void* l) {
  __builtin_amdgcn_global_load_lds((const __attribute__((address_space(1))) void*)g,
                                   (__attribute__((address_space(3))) void*)l, 16, 0, 0);
}

// ---------------- prep kernels ----------------

__global__ void k_zero(u16x8* __restrict__ p, int n8) {
  int i = blockIdx.x * blockDim.x + threadIdx.x;
  int stride = gridDim.x * blockDim.x;
  u16x8 z = (u16x8)0;
  for (; i < n8; i += stride) p[i] = z;
}

__global__ void k_cvt_x(const float* __restrict__ in, u16* __restrict__ out, int n4) {
  int i = blockIdx.x * blockDim.x + threadIdx.x;
  int stride = gridDim.x * blockDim.x;
  const f32x4* in4 = (const f32x4*)in;
  u16x4* out4 = (u16x4*)out;
  for (; i < n4; i += stride) {
    f32x4 v = in4[i];
    u16x4 o;
    o[0] = f2bf(v[0]); o[1] = f2bf(v[1]); o[2] = f2bf(v[2]); o[3] = f2bf(v[3]);
    out4[i] = o;
  }
}

// LDS-tiled transpose: w [K][1024] f32 -> outT [1024][K] bf16, 64x64 tiles.
__global__ void k_prep_wt(const float* __restrict__ wq, const float* __restrict__ wo,
                          const float* __restrict__ wk, const float* __restrict__ wv,
                          u16* __restrict__ WQ1T, u16* __restrict__ WO1T,
                          u16* __restrict__ WK1T, u16* __restrict__ WV1T) {
  __shared__ u16 tile[64][72];
  int bid = blockIdx.x;
  const float* w; u16* o; int K;
  if (bid < 256)      { w = wq; o = WQ1T; K = 1024; }
  else if (bid < 512) { w = wo; o = WO1T; K = 1024; bid -= 256; }
  else if (bid < 704) { w = wk; o = WK1T; K = 768;  bid -= 512; }
  else                { w = wv; o = WV1T; K = 768;  bid -= 704; }
  const int ti = bid >> 4, tj = bid & 15;
  const int t = threadIdx.x;
  const int r = t >> 2, cq = (t & 3) * 16;

  const float* src = w + (size_t)(ti * 64 + r) * 1024 + tj * 64 + cq;
#pragma unroll
  for (int j4 = 0; j4 < 4; ++j4) {
    f32x4 v = *(const f32x4*)(src + j4 * 4);
#pragma unroll
    for (int e = 0; e < 4; ++e) tile[r][cq + j4 * 4 + e] = f2bf(v[e]);
  }
  __syncthreads();

  u16 vals[16];
#pragma unroll
  for (int j = 0; j < 16; ++j) vals[j] = tile[cq + j][r];
  u16* dst = o + (size_t)(tj * 64 + r) * K + ti * 64 + cq;
  *(u16x8*)dst = *(u16x8*)&vals[0];
  *(u16x8*)(dst + 8) = *(u16x8*)&vals[8];
}

// y [1232][768] f32 -> yb bf16 (straight cvt)
__global__ void k_prep_y(const float* __restrict__ y, u16* __restrict__ yb, int n4) {
  int i = blockIdx.x * blockDim.x + threadIdx.x;
  int stride = gridDim.x * blockDim.x;
  const f32x4* in4 = (const f32x4*)y;
  u16x4* out4 = (u16x4*)yb;
  for (; i < n4; i += stride) {
    f32x4 v = in4[i];
    u16x4 o;
    o[0] = f2bf(v[0]); o[1] = f2bf(v[1]); o[2] = f2bf(v[2]); o[3] = f2bf(v[3]);
    out4[i] = o;
  }
}

// ---------------- K+V projections, merged, m97-style 128^2 ----------------
__global__ __launch_bounds__(256, 2) void k_gemm_kv(
    const u16* __restrict__ A,
    const u16* __restrict__ BK1, const float* __restrict__ bkb, u16* __restrict__ KTo,
    const u16* __restrict__ BV1, const float* __restrict__ bvb, u16* __restrict__ VTo)
{
  const int M = 1232, Kdim = 768;
  __shared__ u16 sA[128 * 32];
  __shared__ u16 sB[128 * 32];
  const int t = threadIdx.x;
  const int half = blockIdx.x >= 80;
  const int bb = blockIdx.x - half * 80;
  const u16* B = half ? BV1 : BK1;
  const float* bias = half ? bvb : bkb;
  u16* outp = half ? VTo : KTo;
  const int bm = bb / 8, bn = bb % 8;
  const int m0 = bm * 128, n0 = bn * 128;
  const int l = t & 63, wv_ = t >> 6;
  const int lr = l & 15, lg = l >> 4;
  const int wm = (wv_ >> 1) * 64, wn = (wv_ & 1) * 64;

  const int srow = t >> 2;
  const int ssw = ((t >> 2) & 3) ^ ((t >> 4) & 3);
  const int scol = ((t & 3) ^ ssw) * 8;
  char* ldsA = (char*)sA;
  char* ldsB = (char*)sB;
  const int ldsoff = wv_ * 1024;

  const int swl = (lr & 3) ^ ((lr >> 2) & 3);
  const int rds = (lg ^ swl) * 8;

  f32x4 acc[4][4] = {};

  for (int kt = 0; kt < Kdim / 32; ++kt) {
    const int k0 = kt * 32;
    __syncthreads();
    {
      int r1 = m0 + srow;       if (r1 > M - 1) r1 = M - 1;
      int r2 = m0 + 64 + srow;  if (r2 > M - 1) r2 = M - 1;
      gload_lds16(A + (size_t)r1 * Kdim + k0 + scol, ldsA + 0    + ldsoff);
      gload_lds16(A + (size_t)r2 * Kdim + k0 + scol, ldsA + 4096 + ldsoff);
      gload_lds16(B + (size_t)(n0 + srow) * Kdim + k0 + scol,      ldsB + 0    + ldsoff);
      gload_lds16(B + (size_t)(n0 + 64 + srow) * Kdim + k0 + scol, ldsB + 4096 + ldsoff);
    }
    __syncthreads();
    bf16x8 af[4], bfr[4];
#pragma unroll
    for (int mt = 0; mt < 4; ++mt)
      af[mt] = *(const bf16x8*)&sA[(wm + mt * 16 + lr) * 32 + rds];
#pragma unroll
    for (int nt = 0; nt < 4; ++nt)
      bfr[nt] = *(const bf16x8*)&sB[(wn + nt * 16 + lr) * 32 + rds];
#pragma unroll
    for (int mt = 0; mt < 4; ++mt)
#pragma unroll
      for (int nt = 0; nt < 4; ++nt)
        acc[mt][nt] = __builtin_amdgcn_mfma_f32_16x16x32_bf16(af[mt], bfr[nt], acc[mt][nt], 0, 0, 0);
  }

#pragma unroll
  for (int mt = 0; mt < 4; ++mt) {
#pragma unroll
    for (int nt = 0; nt < 4; ++nt) {
      const int gc = n0 + wn + nt * 16 + lr;
      const float bb2 = bias[gc];
#pragma unroll
      for (int r = 0; r < 4; ++r) {
        const int gr = m0 + wm + mt * 16 + lg * 4 + r;
        const float v = acc[mt][nt][r] + bb2;
        if (gr < M) {
          int bI = gr / 77, s = gr - bI * 77;
          int hh = gc >> 6, d = gc & 63;
          if (!half)
            outp[(((size_t)bI * 16 + hh) * 96 + s) * 64 + d] = f2bf(v);
          else
            outp[(((size_t)bI * 16 + hh) * 64 + d) * 96 + s] = f2bf(v);
        }
      }
    }
  }
}

// ---------------- big GEMM: 256x256, BK=32, A-only LDS (3 bufs), B via registers ----------------
// Identical to round 9 EXCEPT __launch_bounds__(512, 2): r9's (512,6) capped VGPR at ~85,
// spilling the 128-VGPR accumulator to scratch (VGPR_Count=40, FETCH 5GB, MfmaUtil 1.3%).
// At (512,2): cap 256 VGPR, acc+Bfrags fit, 2 waves/SIMD, 1 block/CU.
// Pipe model per CU per K-tile: LDS = 64 ds_read_b128 (~770cyc) + stage-writes (~160)
// < MFMA 256x4.85 (~1242cyc) -> MFMA is the only saturated pipe.
// Ledger (unchanged, numerically verified in r9): each half-iter issues 6 [B:4, A-stage:2];
// vmcnt(6) retires everything except own issues -> B(n), A(n+1) landed before BAR.
template <int EPI>
__global__ __launch_bounds__(512, 2) void gemm256(
    const u16* __restrict__ A, const u16* __restrict__ Bp,
    const float* __restrict__ bias, void* __restrict__ outp)
{
  __shared__ char lds[49152];
  const int t = threadIdx.x;
  const int cpx = (int)gridDim.x >> 3;
  const int swz = ((int)blockIdx.x & 7) * cpx + ((int)blockIdx.x >> 3);
  const int bm = swz >> 2, bn = swz & 3;
  const int m0 = bm * 256, n0 = bn * 256;
  const int w = t >> 6, l = t & 63, lr = l & 15, lg = l >> 4;
  const int wm = w >> 2, wn = w & 3;   // 2 M-waves x 4 N-waves, wave tile 128x64

  const int srow = t >> 2;
  const int scol = ((t & 3) ^ ((t >> 2) & 3) ^ ((t >> 4) & 3)) * 8;  // elems
  const int rsw = (lg ^ (lr & 3) ^ ((lr >> 2) & 3)) << 4;            // read swizzle, bytes
  const int arow = wm * 128 + lr;

  // B per-lane base: col = n0 + wn*64 + nt*16 + lr, k = kt*32 + lg*8
  const u16* bptr = Bp + (size_t)(n0 + wn * 64 + lr) * 1024 + lg * 8;

  f32x4 acc[8][4] = {};

#define RD_A(dst, rbb) { _Pragma("unroll") for (int q = 0; q < 8; ++q) \
    dst[q] = *(const bf16x8*)(lds + (rbb) + ((arow + q * 16) << 6) + rsw); }
#define LD_B(dst, kt) { _Pragma("unroll") for (int nt = 0; nt < 4; ++nt) \
    dst[nt] = *(const bf16x8*)(bptr + (size_t)nt * 16384 + (kt) * 32); }
#define STAGE_A(kt, sbb) { \
    gload_lds16(A + (size_t)(m0 + srow) * 1024 + (kt) * 32 + scol,       lds + (sbb) + t * 16); \
    gload_lds16(A + (size_t)(m0 + 128 + srow) * 1024 + (kt) * 32 + scol, lds + (sbb) + 8192 + t * 16); }
#define MM(a_, b_) { __builtin_amdgcn_s_setprio(1); \
  _Pragma("unroll") for (int q = 0; q < 8; ++q) \
    _Pragma("unroll") for (int nt = 0; nt < 4; ++nt) \
      acc[q][nt] = __builtin_amdgcn_mfma_f32_16x16x32_bf16(a_[q], b_[nt], acc[q][nt], 0, 0, 0); \
  __builtin_amdgcn_s_setprio(0); }
#define BAR __builtin_amdgcn_s_barrier()
#define SB0 __builtin_amdgcn_sched_barrier(0)
#define VM6 asm volatile("s_waitcnt vmcnt(6)" ::: "memory")

  bf16x8 bA[4], bB[4];

  // prologue: stage A tiles 0,1; load B(0). vmcnt(6) retires A0.
  STAGE_A(0, 0);
  STAGE_A(1, 16384);
  LD_B(bA, 0);
  VM6; SB0; BAR;

  int rb = 0, sb = 32768;
#pragma unroll 1
  for (int c = 0; c < 32; c += 2) {
    {
      bf16x8 a_[8];
      RD_A(a_, rb);
      LD_B(bB, c + 1);
      int k2 = c + 2; if (k2 > 31) k2 = 31;  // tail: dummy re-stage into retired buf
      STAGE_A(k2, sb);
      VM6; SB0; BAR;
      MM(a_, bA);
      BAR;
      rb += 16384; if (rb == 49152) rb = 0;
      sb += 16384; if (sb == 49152) sb = 0;
    }
    {
      bf16x8 a_[8];
      RD_A(a_, rb);
      int k1 = c + 2; if (k1 > 31) k1 = 31;
      LD_B(bA, k1);
      int k2 = c + 3; if (k2 > 31) k2 = 31;
      STAGE_A(k2, sb);
      VM6; SB0; BAR;
      MM(a_, bB);
      BAR;
      rb += 16384; if (rb == 49152) rb = 0;
      sb += 16384; if (sb == 49152) sb = 0;
    }
  }
  asm volatile("s_waitcnt vmcnt(0)" ::: "memory");  // drain dummy stages before endpgm
  SB0;

#undef RD_A
#undef LD_B
#undef STAGE_A
#undef MM
#undef BAR
#undef SB0
#undef VM6

  // epilogue: C row = m0 + wm*128 + q*16 + lg*4 + r ; col = n0 + wn*64 + nt*16 + lr
#pragma unroll
  for (int q = 0; q < 8; ++q) {
#pragma unroll
    for (int nt = 0; nt < 4; ++nt) {
      const int gc = n0 + wn * 64 + nt * 16 + lr;
      const float bb = bias[gc];
#pragma unroll
      for (int r = 0; r < 4; ++r) {
        const int gr = m0 + wm * 128 + q * 16 + lg * 4 + r;
        const float v = acc[q][nt][r] + bb;
        if constexpr (EPI == 0) {
          ((u16*)outp)[(size_t)gr * 1024 + gc] = f2bf(v);
        } else {
          ((float*)outp)[(size_t)gr * 1024 + gc] = v;
        }
      }
    }
  }
}

// ---------------- fused attention ----------------
__global__ __launch_bounds__(256) void k_attn(const u16* __restrict__ KT,
                                              const u16* __restrict__ VT,
                                              u16* __restrict__ QB)
{
  __shared__ u16 sK[96 * 72];
  __shared__ u16 sV[64 * 104];
  __shared__ u16 sP[4][32 * 104];

  const int bid = blockIdx.x;
  const int h = bid & 15, b = (bid >> 4) & 15, blk = bid >> 8;
  const int t = threadIdx.x;

  const u16* gK = KT + (size_t)(b * 16 + h) * (96 * 64);
  const u16* gV = VT + (size_t)(b * 16 + h) * (64 * 96);
#pragma unroll
  for (int c = 0; c < 3; ++c) {
    int e = t * 8 + c * 2048;
    { int row = e >> 6, col = e & 63;
      *(u16x8*)&sK[row * 72 + col] = *(const u16x8*)&gK[e]; }
    { int row = e / 96, col = e - (e / 96) * 96;
      *(u16x8*)&sV[row * 104 + col] = *(const u16x8*)&gV[e]; }
  }
  __syncthreads();

  const int l = t & 63, w = t >> 6, lr = l & 15, lg = l >> 4;
  const size_t rowbase = (size_t)b * 4096 + blk * 128 + w * 32;

  bf16x8 aq[2][2];
#pragma unroll
  for (int mt = 0; mt < 2; ++mt)
#pragma unroll
    for (int ks = 0; ks < 2; ++ks)
      aq[mt][ks] = *(const bf16x8*)&QB[(rowbase + mt * 16 + lr) * 1024 + h * 64 + ks * 32 + lg * 8];

  f32x4 s_[2][5] = {};
#pragma unroll
  for (int nt = 0; nt < 5; ++nt) {
#pragma unroll
    for (int ks = 0; ks < 2; ++ks) {
      bf16x8 bk = *(const bf16x8*)&sK[(nt * 16 + lr) * 72 + ks * 32 + lg * 8];
#pragma unroll
      for (int mt = 0; mt < 2; ++mt)
        s_[mt][nt] = __builtin_amdgcn_mfma_f32_16x16x32_bf16(aq[mt][ks], bk, s_[mt][nt], 0, 0, 0);
    }
  }
#pragma unroll
  for (int mt = 0; mt < 2; ++mt)
#pragma unroll
    for (int nt = 0; nt < 5; ++nt)
#pragma unroll
      for (int r = 0; r < 4; ++r)
        s_[mt][nt][r] *= 0.125f;
  if (lr >= 13) {
#pragma unroll
    for (int mt = 0; mt < 2; ++mt)
#pragma unroll
      for (int r = 0; r < 4; ++r)
        s_[mt][4][r] = -1e30f;
  }

  float ri[2][4];
#pragma unroll
  for (int mt = 0; mt < 2; ++mt) {
#pragma unroll
    for (int r = 0; r < 4; ++r) {
      float m1 = s_[mt][0][r];
#pragma unroll
      for (int nt = 1; nt < 5; ++nt) m1 = fmaxf(m1, s_[mt][nt][r]);
      m1 = fmaxf(m1, __shfl_xor(m1, 1, 64));
      m1 = fmaxf(m1, __shfl_xor(m1, 2, 64));
      m1 = fmaxf(m1, __shfl_xor(m1, 4, 64));
      m1 = fmaxf(m1, __shfl_xor(m1, 8, 64));
      float s1 = 0.f;
#pragma unroll
      for (int nt = 0; nt < 5; ++nt) {
        float e = __expf(s_[mt][nt][r] - m1);
        s_[mt][nt][r] = e;
        s1 += e;
      }
      s1 += __shfl_xor(s1, 1, 64);
      s1 += __shfl_xor(s1, 2, 64);
      s1 += __shfl_xor(s1, 4, 64);
      s1 += __shfl_xor(s1, 8, 64);
      ri[mt][r] = 1.0f / s1;
    }
  }

#pragma unroll
  for (int mt = 0; mt < 2; ++mt)
#pragma unroll
    for (int nt = 0; nt < 5; ++nt)
#pragma unroll
      for (int r = 0; r < 4; ++r)
        sP[w][(mt * 16 + lg * 4 + r) * 104 + nt * 16 + lr] = f2bf(s_[mt][nt][r] * ri[mt][r]);
#pragma unroll
  for (int mt = 0; mt < 2; ++mt)
#pragma unroll
    for (int r = 0; r < 4; ++r)
      sP[w][(mt * 16 + lg * 4 + r) * 104 + 80 + lr] = 0;

  f32x4 o_[2][4] = {};
#pragma unroll
  for (int ks = 0; ks < 3; ++ks) {
    bf16x8 ap[2];
#pragma unroll
    for (int mt = 0; mt < 2; ++mt)
      ap[mt] = *(const bf16x8*)&sP[w][(mt * 16 + lr) * 104 + ks * 32 + lg * 8];
#pragma unroll
    for (int nt = 0; nt < 4; ++nt) {
      bf16x8 bv = *(const bf16x8*)&sV[(nt * 16 + lr) * 104 + ks * 32 + lg * 8];
#pragma unroll
      for (int mt = 0; mt < 2; ++mt)
        o_[mt][nt] = __builtin_amdgcn_mfma_f32_16x16x32_bf16(ap[mt], bv, o_[mt][nt], 0, 0, 0);
    }
  }

#pragma unroll
  for (int mt = 0; mt < 2; ++mt)
#pragma unroll
    for (int nt = 0; nt < 4; ++nt)
#pragma unroll
      for (int r = 0; r < 4; ++r)
        QB[(rowbase + mt * 16 + lg * 4 + r) * 1024 + h * 64 + nt * 16 + lr] = f2bf(o_[mt][nt][r]);
}

// ---------------- launch ----------------

extern "C" void kernel_launch(void* const* d_in, const int* in_sizes, int n_in,
                              void* d_out, int out_size, void* d_ws, size_t ws_size,
                              hipStream_t stream) {
  const float* x  = (const float*)d_in[0];
  const float* y  = (const float*)d_in[1];
  const float* wq = (const float*)d_in[2];
  const float* bq = (const float*)d_in[3];
  const float* wk = (const float*)d_in[4];
  const float* bk = (const float*)d_in[5];
  const float* wv = (const float*)d_in[6];
  const float* bv = (const float*)d_in[7];
  const float* wo = (const float*)d_in[8];
  const float* bo = (const float*)d_in[9];

  char* ws = (char*)d_ws;
  u16* QB   = (u16*)(ws + 0);            // 65536x1024 bf16 = 128 MB (Q, then attn out in-place)
  u16* WQ1T = (u16*)(ws + 134217728);    // [1024][1024] bf16, 2 MB
  u16* WO1T = (u16*)(ws + 136314880);    // 2 MB
  u16* WK1T = (u16*)(ws + 138412032);    // [1024][768] bf16, 1.5 MB
  u16* WV1T = (u16*)(ws + 139984896);    // 1.5 MB
  u16* YB   = (u16*)(ws + 141557760);    // [1232][768] bf16, 1.85 MB
  u16* KT   = (u16*)(ws + 143654912);    // [16][16][96][64] bf16, 3 MB
  u16* VT   = (u16*)(ws + 146800640);    // [16][16][64][96] bf16, 3 MB

  u16*   XB  = (u16*)d_out;   // x as bf16, first 128 MB of d_out (consumed before final write)
  float* OUT = (float*)d_out;

  // prep
  k_zero<<<768, 256, 0, stream>>>((u16x8*)KT, 393216);          // zero KT+VT (adjacent, 6 MB)
  k_cvt_x<<<4096, 256, 0, stream>>>(x, XB, 16777216);
  k_prep_wt<<<896, 256, 0, stream>>>(wq, wo, wk, wv, WQ1T, WO1T, WK1T, WV1T);
  k_prep_y<<<924, 256, 0, stream>>>(y, YB, 236544);

  // K+V projections (one launch): M=1232, K=768
  k_gemm_kv<<<160, 256, 0, stream>>>(YB, WK1T, bk, KT, WV1T, bv, VT);

  // Q projection: 256x256 BK=32, A-LDS triple buffer + B-in-regs, grid 256 bm x 4 bn
  gemm256<0><<<1024, 512, 0, stream>>>(XB, WQ1T, bq, QB);

  // fused attention, in-place QB -> attn_out
  k_attn<<<8192, 256, 0, stream>>>(KT, VT, QB);

  // output projection -> f32 d_out
  gemm256<1><<<1024, 512, 0, stream>>>(QB, WO1T, bo, OUT);
}

// Round 11
// 531.533 us; speedup vs baseline: 14.8304x; 1.2547x over previous
//
#include <hip/hip_runtime.h>

typedef unsigned short u16;
typedef __attribute__((ext_vector_type(4))) float f32x4;
typedef __attribute__((ext_vector_type(8))) short bf16x8;
typedef __attribute__((ext_vector_type(8))) unsigned short u16x8;
typedef __attribute__((ext_vector_type(4))) unsigned short u16x4;

__device__ __forceinline__ u16 f2bf(float f) {
  union { float f; unsigned u; } v; v.f = f;
  unsigned r = v.u + 0x7FFFu + ((v.u >> 16) & 1u);
  return (u16)(r >> 16);
}
__device__ __forceinline__ float bf2f(u16 h) {
  union { unsigned u; float f; } v; v.u = ((unsigned)h) << 16; return v.f;
}

__device__ __forceinline__ void gload_lds16(const void* g, void* l) {
  __builtin_amdgcn_global_load_lds((const __attribute__((address_space(1))) void*)g,
                                   (__attribute__((address_space(3))) void*)l, 16, 0, 0);
}

// ---------------- prep kernels ----------------

__global__ void k_zero(u16x8* __restrict__ p, int n8) {
  int i = blockIdx.x * blockDim.x + threadIdx.x;
  int stride = gridDim.x * blockDim.x;
  u16x8 z = (u16x8)0;
  for (; i < n8; i += stride) p[i] = z;
}

__global__ void k_cvt_x(const float* __restrict__ in, u16* __restrict__ out, int n4) {
  int i = blockIdx.x * blockDim.x + threadIdx.x;
  int stride = gridDim.x * blockDim.x;
  const f32x4* in4 = (const f32x4*)in;
  u16x4* out4 = (u16x4*)out;
  for (; i < n4; i += stride) {
    f32x4 v = in4[i];
    u16x4 o;
    o[0] = f2bf(v[0]); o[1] = f2bf(v[1]); o[2] = f2bf(v[2]); o[3] = f2bf(v[3]);
    out4[i] = o;
  }
}

// LDS-tiled transpose: w [K][1024] f32 -> outT [1024][K] bf16, 64x64 tiles.
__global__ void k_prep_wt(const float* __restrict__ wq, const float* __restrict__ wo,
                          const float* __restrict__ wk, const float* __restrict__ wv,
                          u16* __restrict__ WQ1T, u16* __restrict__ WO1T,
                          u16* __restrict__ WK1T, u16* __restrict__ WV1T) {
  __shared__ u16 tile[64][72];
  int bid = blockIdx.x;
  const float* w; u16* o; int K;
  if (bid < 256)      { w = wq; o = WQ1T; K = 1024; }
  else if (bid < 512) { w = wo; o = WO1T; K = 1024; bid -= 256; }
  else if (bid < 704) { w = wk; o = WK1T; K = 768;  bid -= 512; }
  else                { w = wv; o = WV1T; K = 768;  bid -= 704; }
  const int ti = bid >> 4, tj = bid & 15;
  const int t = threadIdx.x;
  const int r = t >> 2, cq = (t & 3) * 16;

  const float* src = w + (size_t)(ti * 64 + r) * 1024 + tj * 64 + cq;
#pragma unroll
  for (int j4 = 0; j4 < 4; ++j4) {
    f32x4 v = *(const f32x4*)(src + j4 * 4);
#pragma unroll
    for (int e = 0; e < 4; ++e) tile[r][cq + j4 * 4 + e] = f2bf(v[e]);
  }
  __syncthreads();

  u16 vals[16];
#pragma unroll
  for (int j = 0; j < 16; ++j) vals[j] = tile[cq + j][r];
  u16* dst = o + (size_t)(tj * 64 + r) * K + ti * 64 + cq;
  *(u16x8*)dst = *(u16x8*)&vals[0];
  *(u16x8*)(dst + 8) = *(u16x8*)&vals[8];
}

// y [1232][768] f32 -> yb bf16 (straight cvt)
__global__ void k_prep_y(const float* __restrict__ y, u16* __restrict__ yb, int n4) {
  int i = blockIdx.x * blockDim.x + threadIdx.x;
  int stride = gridDim.x * blockDim.x;
  const f32x4* in4 = (const f32x4*)y;
  u16x4* out4 = (u16x4*)yb;
  for (; i < n4; i += stride) {
    f32x4 v = in4[i];
    u16x4 o;
    o[0] = f2bf(v[0]); o[1] = f2bf(v[1]); o[2] = f2bf(v[2]); o[3] = f2bf(v[3]);
    out4[i] = o;
  }
}

// ---------------- K+V projections, merged, m97-style 128^2 ----------------
__global__ __launch_bounds__(256, 2) void k_gemm_kv(
    const u16* __restrict__ A,
    const u16* __restrict__ BK1, const float* __restrict__ bkb, u16* __restrict__ KTo,
    const u16* __restrict__ BV1, const float* __restrict__ bvb, u16* __restrict__ VTo)
{
  const int M = 1232, Kdim = 768;
  __shared__ u16 sA[128 * 32];
  __shared__ u16 sB[128 * 32];
  const int t = threadIdx.x;
  const int half = blockIdx.x >= 80;
  const int bb = blockIdx.x - half * 80;
  const u16* B = half ? BV1 : BK1;
  const float* bias = half ? bvb : bkb;
  u16* outp = half ? VTo : KTo;
  const int bm = bb / 8, bn = bb % 8;
  const int m0 = bm * 128, n0 = bn * 128;
  const int l = t & 63, wv_ = t >> 6;
  const int lr = l & 15, lg = l >> 4;
  const int wm = (wv_ >> 1) * 64, wn = (wv_ & 1) * 64;

  const int srow = t >> 2;
  const int ssw = ((t >> 2) & 3) ^ ((t >> 4) & 3);
  const int scol = ((t & 3) ^ ssw) * 8;
  char* ldsA = (char*)sA;
  char* ldsB = (char*)sB;
  const int ldsoff = wv_ * 1024;

  const int swl = (lr & 3) ^ ((lr >> 2) & 3);
  const int rds = (lg ^ swl) * 8;

  f32x4 acc[4][4] = {};

  for (int kt = 0; kt < Kdim / 32; ++kt) {
    const int k0 = kt * 32;
    __syncthreads();
    {
      int r1 = m0 + srow;       if (r1 > M - 1) r1 = M - 1;
      int r2 = m0 + 64 + srow;  if (r2 > M - 1) r2 = M - 1;
      gload_lds16(A + (size_t)r1 * Kdim + k0 + scol, ldsA + 0    + ldsoff);
      gload_lds16(A + (size_t)r2 * Kdim + k0 + scol, ldsA + 4096 + ldsoff);
      gload_lds16(B + (size_t)(n0 + srow) * Kdim + k0 + scol,      ldsB + 0    + ldsoff);
      gload_lds16(B + (size_t)(n0 + 64 + srow) * Kdim + k0 + scol, ldsB + 4096 + ldsoff);
    }
    __syncthreads();
    bf16x8 af[4], bfr[4];
#pragma unroll
    for (int mt = 0; mt < 4; ++mt)
      af[mt] = *(const bf16x8*)&sA[(wm + mt * 16 + lr) * 32 + rds];
#pragma unroll
    for (int nt = 0; nt < 4; ++nt)
      bfr[nt] = *(const bf16x8*)&sB[(wn + nt * 16 + lr) * 32 + rds];
#pragma unroll
    for (int mt = 0; mt < 4; ++mt)
#pragma unroll
      for (int nt = 0; nt < 4; ++nt)
        acc[mt][nt] = __builtin_amdgcn_mfma_f32_16x16x32_bf16(af[mt], bfr[nt], acc[mt][nt], 0, 0, 0);
  }

#pragma unroll
  for (int mt = 0; mt < 4; ++mt) {
#pragma unroll
    for (int nt = 0; nt < 4; ++nt) {
      const int gc = n0 + wn + nt * 16 + lr;
      const float bb2 = bias[gc];
#pragma unroll
      for (int r = 0; r < 4; ++r) {
        const int gr = m0 + wm + mt * 16 + lg * 4 + r;
        const float v = acc[mt][nt][r] + bb2;
        if (gr < M) {
          int bI = gr / 77, s = gr - bI * 77;
          int hh = gc >> 6, d = gc & 63;
          if (!half)
            outp[(((size_t)bI * 16 + hh) * 96 + s) * 64 + d] = f2bf(v);
          else
            outp[(((size_t)bI * 16 + hh) * 64 + d) * 96 + s] = f2bf(v);
        }
      }
    }
  }
}

// ---------------- big GEMM: 256x256, BK=32, 4-slot LDS ring, reg-dbuf read prefetch ----------------
// M=65536, N=1024, K=1024. A [M][1024] bf16, B^T [1024][1024] bf16.
// 512 thr = 8 waves (2M x 4N), wave tile 128x64: 12 ds_read_b128 + 32 MFMA per tile.
// KEY CHANGE vs r6/r8 (both ~34%, LDS+MFMA serialized): ds_reads moved AFTER BAR1 and
// read tile c+1 into the spare register set while MM consumes tile c's set. Reads and
// MFMAs are independent -> compiler emits lgkmcnt(12) (waits only prior body's reads);
// LDS pipe (1152cyc/CU/tile) overlaps MFMA pipe (1242cyc/CU/tile).
// Ring: 4 slots x 32KB (A 16KB + B 16KB) = 128KB, 1 block/CU. Stage tile c+3 at body c.
// Ledger at vmcnt(8): outstanding [c+1:4, c+2:4, c+3:4] -> retires tile c+1 exactly,
// which is what the RD after BAR consumes. Waits BEFORE barriers (r7 lesson).
// Slot overwrite distance: slot read at body c restaged at body c+2, with >=3 barriers
// and an lgkmcnt-consume in between. Tail: dummy re-stages into retired slots; final
// garbage RD (tile 32) reads a quiescent slot and is never consumed.
template <int EPI>
__global__ __launch_bounds__(512, 2) void gemm256(
    const u16* __restrict__ A, const u16* __restrict__ Bp,
    const float* __restrict__ bias, void* __restrict__ outp)
{
  __shared__ char lds[131072];
  const int t = threadIdx.x;
  const int cpx = (int)gridDim.x >> 3;
  const int swz = ((int)blockIdx.x & 7) * cpx + ((int)blockIdx.x >> 3);
  const int bm = swz >> 2, bn = swz & 3;
  const int m0 = bm * 256, n0 = bn * 256;
  const int w = t >> 6, l = t & 63, lr = l & 15, lg = l >> 4;
  const int wm = w >> 2, wn = w & 3;   // 2 M-waves x 4 N-waves, wave tile 128x64

  const int srow = t >> 2;
  const int scol = ((t & 3) ^ ((t >> 2) & 3) ^ ((t >> 4) & 3)) * 8;  // elems
  const int rsw = (lg ^ (lr & 3) ^ ((lr >> 2) & 3)) << 4;            // bytes
  const int arow = wm * 128 + lr;
  const int brow = wn * 64 + lr;

  f32x4 acc[8][4] = {};

#define RD(dstA, dstB, sbb) { \
  _Pragma("unroll") for (int q = 0; q < 8; ++q) \
    dstA[q] = *(const bf16x8*)(lds + (sbb) + ((arow + q * 16) << 6) + rsw); \
  _Pragma("unroll") for (int nt = 0; nt < 4; ++nt) \
    dstB[nt] = *(const bf16x8*)(lds + (sbb) + 16384 + ((brow + nt * 16) << 6) + rsw); }
#define STAGE(kt, sbb) { \
    gload_lds16(A  + (size_t)(m0 + srow) * 1024 + (kt) * 32 + scol,       lds + (sbb) + t * 16); \
    gload_lds16(A  + (size_t)(m0 + 128 + srow) * 1024 + (kt) * 32 + scol, lds + (sbb) + 8192 + t * 16); \
    gload_lds16(Bp + (size_t)(n0 + srow) * 1024 + (kt) * 32 + scol,       lds + (sbb) + 16384 + t * 16); \
    gload_lds16(Bp + (size_t)(n0 + 128 + srow) * 1024 + (kt) * 32 + scol, lds + (sbb) + 24576 + t * 16); }
#define MM(a_, b_) { __builtin_amdgcn_s_setprio(1); \
  _Pragma("unroll") for (int q = 0; q < 8; ++q) \
    _Pragma("unroll") for (int nt = 0; nt < 4; ++nt) \
      acc[q][nt] = __builtin_amdgcn_mfma_f32_16x16x32_bf16(a_[q], b_[nt], acc[q][nt], 0, 0, 0); \
  __builtin_amdgcn_s_setprio(0); }
#define BAR __builtin_amdgcn_s_barrier()
#define SB0 __builtin_amdgcn_sched_barrier(0)
#define VM8 asm volatile("s_waitcnt vmcnt(8)" ::: "memory")

  bf16x8 aA[8], bA[4], aB[8], bB[4];

  // prologue: stage tiles 0,1,2 into slots 0,1,2; vmcnt(8) retires tile 0; read it.
  STAGE(0, 0); STAGE(1, 32768); STAGE(2, 65536);
  VM8; SB0; BAR;
  RD(aA, bA, 0);

  int rdo = 32768, sto = 98304;
#pragma unroll 1
  for (int tt = 0; tt < 32; tt += 2) {
    { // body A: consume tile tt (aA/bA), prefetch-read tile tt+1 into aB/bB
      int ks = tt + 3; if (ks > 31) ks = 31;
      STAGE(ks, sto); sto = (sto + 32768) & 131071;
      VM8; SB0; BAR;
      RD(aB, bB, rdo); rdo = (rdo + 32768) & 131071;
      MM(aA, bA);
      BAR;
    }
    { // body B: consume tile tt+1 (aB/bB), prefetch-read tile tt+2 into aA/bA
      int ks = tt + 4; if (ks > 31) ks = 31;
      STAGE(ks, sto); sto = (sto + 32768) & 131071;
      VM8; SB0; BAR;
      RD(aA, bA, rdo); rdo = (rdo + 32768) & 131071;
      MM(aB, bB);
      BAR;
    }
  }
  asm volatile("s_waitcnt vmcnt(0)" ::: "memory");  // drain dummy stages before endpgm
  SB0;

#undef RD
#undef STAGE
#undef MM
#undef BAR
#undef SB0
#undef VM8

  // epilogue: C row = m0 + wm*128 + q*16 + lg*4 + r ; col = n0 + wn*64 + nt*16 + lr
#pragma unroll
  for (int q = 0; q < 8; ++q) {
#pragma unroll
    for (int nt = 0; nt < 4; ++nt) {
      const int gc = n0 + wn * 64 + nt * 16 + lr;
      const float bb = bias[gc];
#pragma unroll
      for (int r = 0; r < 4; ++r) {
        const int gr = m0 + wm * 128 + q * 16 + lg * 4 + r;
        const float v = acc[q][nt][r] + bb;
        if constexpr (EPI == 0) {
          ((u16*)outp)[(size_t)gr * 1024 + gc] = f2bf(v);
        } else {
          ((float*)outp)[(size_t)gr * 1024 + gc] = v;
        }
      }
    }
  }
}

// ---------------- fused attention ----------------
__global__ __launch_bounds__(256) void k_attn(const u16* __restrict__ KT,
                                              const u16* __restrict__ VT,
                                              u16* __restrict__ QB)
{
  __shared__ u16 sK[96 * 72];
  __shared__ u16 sV[64 * 104];
  __shared__ u16 sP[4][32 * 104];

  const int bid = blockIdx.x;
  const int h = bid & 15, b = (bid >> 4) & 15, blk = bid >> 8;
  const int t = threadIdx.x;

  const u16* gK = KT + (size_t)(b * 16 + h) * (96 * 64);
  const u16* gV = VT + (size_t)(b * 16 + h) * (64 * 96);
#pragma unroll
  for (int c = 0; c < 3; ++c) {
    int e = t * 8 + c * 2048;
    { int row = e >> 6, col = e & 63;
      *(u16x8*)&sK[row * 72 + col] = *(const u16x8*)&gK[e]; }
    { int row = e / 96, col = e - (e / 96) * 96;
      *(u16x8*)&sV[row * 104 + col] = *(const u16x8*)&gV[e]; }
  }
  __syncthreads();

  const int l = t & 63, w = t >> 6, lr = l & 15, lg = l >> 4;
  const size_t rowbase = (size_t)b * 4096 + blk * 128 + w * 32;

  bf16x8 aq[2][2];
#pragma unroll
  for (int mt = 0; mt < 2; ++mt)
#pragma unroll
    for (int ks = 0; ks < 2; ++ks)
      aq[mt][ks] = *(const bf16x8*)&QB[(rowbase + mt * 16 + lr) * 1024 + h * 64 + ks * 32 + lg * 8];

  f32x4 s_[2][5] = {};
#pragma unroll
  for (int nt = 0; nt < 5; ++nt) {
#pragma unroll
    for (int ks = 0; ks < 2; ++ks) {
      bf16x8 bk = *(const bf16x8*)&sK[(nt * 16 + lr) * 72 + ks * 32 + lg * 8];
#pragma unroll
      for (int mt = 0; mt < 2; ++mt)
        s_[mt][nt] = __builtin_amdgcn_mfma_f32_16x16x32_bf16(aq[mt][ks], bk, s_[mt][nt], 0, 0, 0);
    }
  }
#pragma unroll
  for (int mt = 0; mt < 2; ++mt)
#pragma unroll
    for (int nt = 0; nt < 5; ++nt)
#pragma unroll
      for (int r = 0; r < 4; ++r)
        s_[mt][nt][r] *= 0.125f;
  if (lr >= 13) {
#pragma unroll
    for (int mt = 0; mt < 2; ++mt)
#pragma unroll
      for (int r = 0; r < 4; ++r)
        s_[mt][4][r] = -1e30f;
  }

  float ri[2][4];
#pragma unroll
  for (int mt = 0; mt < 2; ++mt) {
#pragma unroll
    for (int r = 0; r < 4; ++r) {
      float m1 = s_[mt][0][r];
#pragma unroll
      for (int nt = 1; nt < 5; ++nt) m1 = fmaxf(m1, s_[mt][nt][r]);
      m1 = fmaxf(m1, __shfl_xor(m1, 1, 64));
      m1 = fmaxf(m1, __shfl_xor(m1, 2, 64));
      m1 = fmaxf(m1, __shfl_xor(m1, 4, 64));
      m1 = fmaxf(m1, __shfl_xor(m1, 8, 64));
      float s1 = 0.f;
#pragma unroll
      for (int nt = 0; nt < 5; ++nt) {
        float e = __expf(s_[mt][nt][r] - m1);
        s_[mt][nt][r] = e;
        s1 += e;
      }
      s1 += __shfl_xor(s1, 1, 64);
      s1 += __shfl_xor(s1, 2, 64);
      s1 += __shfl_xor(s1, 4, 64);
      s1 += __shfl_xor(s1, 8, 64);
      ri[mt][r] = 1.0f / s1;
    }
  }

#pragma unroll
  for (int mt = 0; mt < 2; ++mt)
#pragma unroll
    for (int nt = 0; nt < 5; ++nt)
#pragma unroll
      for (int r = 0; r < 4; ++r)
        sP[w][(mt * 16 + lg * 4 + r) * 104 + nt * 16 + lr] = f2bf(s_[mt][nt][r] * ri[mt][r]);
#pragma unroll
  for (int mt = 0; mt < 2; ++mt)
#pragma unroll
    for (int r = 0; r < 4; ++r)
      sP[w][(mt * 16 + lg * 4 + r) * 104 + 80 + lr] = 0;

  f32x4 o_[2][4] = {};
#pragma unroll
  for (int ks = 0; ks < 3; ++ks) {
    bf16x8 ap[2];
#pragma unroll
    for (int mt = 0; mt < 2; ++mt)
      ap[mt] = *(const bf16x8*)&sP[w][(mt * 16 + lr) * 104 + ks * 32 + lg * 8];
#pragma unroll
    for (int nt = 0; nt < 4; ++nt) {
      bf16x8 bv = *(const bf16x8*)&sV[(nt * 16 + lr) * 104 + ks * 32 + lg * 8];
#pragma unroll
      for (int mt = 0; mt < 2; ++mt)
        o_[mt][nt] = __builtin_amdgcn_mfma_f32_16x16x32_bf16(ap[mt], bv, o_[mt][nt], 0, 0, 0);
    }
  }

#pragma unroll
  for (int mt = 0; mt < 2; ++mt)
#pragma unroll
    for (int nt = 0; nt < 4; ++nt)
#pragma unroll
      for (int r = 0; r < 4; ++r)
        QB[(rowbase + mt * 16 + lg * 4 + r) * 1024 + h * 64 + nt * 16 + lr] = f2bf(o_[mt][nt][r]);
}

// ---------------- launch ----------------

extern "C" void kernel_launch(void* const* d_in, const int* in_sizes, int n_in,
                              void* d_out, int out_size, void* d_ws, size_t ws_size,
                              hipStream_t stream) {
  const float* x  = (const float*)d_in[0];
  const float* y  = (const float*)d_in[1];
  const float* wq = (const float*)d_in[2];
  const float* bq = (const float*)d_in[3];
  const float* wk = (const float*)d_in[4];
  const float* bk = (const float*)d_in[5];
  const float* wv = (const float*)d_in[6];
  const float* bv = (const float*)d_in[7];
  const float* wo = (const float*)d_in[8];
  const float* bo = (const float*)d_in[9];

  char* ws = (char*)d_ws;
  u16* QB   = (u16*)(ws + 0);            // 65536x1024 bf16 = 128 MB (Q, then attn out in-place)
  u16* WQ1T = (u16*)(ws + 134217728);    // [1024][1024] bf16, 2 MB
  u16* WO1T = (u16*)(ws + 136314880);    // 2 MB
  u16* WK1T = (u16*)(ws + 138412032);    // [1024][768] bf16, 1.5 MB
  u16* WV1T = (u16*)(ws + 139984896);    // 1.5 MB
  u16* YB   = (u16*)(ws + 141557760);    // [1232][768] bf16, 1.85 MB
  u16* KT   = (u16*)(ws + 143654912);    // [16][16][96][64] bf16, 3 MB
  u16* VT   = (u16*)(ws + 146800640);    // [16][16][64][96] bf16, 3 MB

  u16*   XB  = (u16*)d_out;   // x as bf16, first 128 MB of d_out (consumed before final write)
  float* OUT = (float*)d_out;

  // prep
  k_zero<<<768, 256, 0, stream>>>((u16x8*)KT, 393216);          // zero KT+VT (adjacent, 6 MB)
  k_cvt_x<<<4096, 256, 0, stream>>>(x, XB, 16777216);
  k_prep_wt<<<896, 256, 0, stream>>>(wq, wo, wk, wv, WQ1T, WO1T, WK1T, WV1T);
  k_prep_y<<<924, 256, 0, stream>>>(y, YB, 236544);

  // K+V projections (one launch): M=1232, K=768
  k_gemm_kv<<<160, 256, 0, stream>>>(YB, WK1T, bk, KT, WV1T, bv, VT);

  // Q projection: 256x256 BK=32, ring-4 + reg-dbuf prefetch, grid 256 bm x 4 bn
  gemm256<0><<<1024, 512, 0, stream>>>(XB, WQ1T, bq, QB);

  // fused attention, in-place QB -> attn_out
  k_attn<<<8192, 256, 0, stream>>>(KT, VT, QB);

  // output projection -> f32 d_out
  gemm256<1><<<1024, 512, 0, stream>>>(QB, WO1T, bo, OUT);
}